// Round 6
// baseline (29.257 us; speedup 1.0000x reference)
//
#include <hip/hip_runtime.h>

#define GRID_N 100
#define T_LEN 2048
#define B_LEN 4096
#define D_LEN 2
#define NBLOCKS 2048
#define NTHREADS (NBLOCKS * 256)      // 524288
#define NWAVES (NTHREADS / 64)        // 8192
#define UNROLL 8
// n4 = B*T*D/4 = 4,194,304 = NTHREADS * UNROLL exactly (no tail)

__device__ __forceinline__ float w2_at(const float* __restrict__ traj2,
                                       const float* __restrict__ gt, int t) {
    float lat = traj2[2 * t + 0];
    float lon = traj2[2 * t + 1];
    int lat_g = (int)floorf((lat + 1.0f) * 50.0f);
    lat_g = min(max(lat_g, 0), GRID_N - 1);
    int lon_g = (int)floorf((lon + 1.0f) * 50.0f);
    lon_g = min(max(lon_g, 0), GRID_N - 1);
    return gt[lat_g * GRID_N + lon_g] * 0.0001f + 1.0f;
}

__global__ void __launch_bounds__(256) main_reduce_kernel(
        const float4* __restrict__ t1,
        const float4* __restrict__ t2,
        const float* __restrict__ traj2s,
        const float* __restrict__ grid_table,
        float* __restrict__ partials) {
    const int tid = blockIdx.x * 256 + threadIdx.x;

    // Load phase: 16 independent float4 loads in flight
    float4 a[UNROLL], b[UNROLL];
    #pragma unroll
    for (int u = 0; u < UNROLL; ++u) {
        int j = tid + u * NTHREADS;
        a[u] = t1[j];
        b[u] = t2[j];
    }

    // This thread's two time indices (constant across all unrolls since
    // NTHREADS % 1024 == 0): t0 = 2*(tid & 1023), covering (t0, t0+1).
    const int t0 = 2 * (tid & (T_LEN * D_LEN / 4 - 1));
    float wA = w2_at(traj2s, grid_table, t0);
    float wB = w2_at(traj2s, grid_table, t0 + 1);

    float accA = 0.0f, accB = 0.0f;
    #pragma unroll
    for (int u = 0; u < UNROLL; ++u) {
        float d0 = a[u].x - b[u].x;
        float d1 = a[u].y - b[u].y;
        float d2 = a[u].z - b[u].z;
        float d3 = a[u].w - b[u].w;
        accA = fmaf(d0, d0, accA);
        accA = fmaf(d1, d1, accA);
        accB = fmaf(d2, d2, accB);
        accB = fmaf(d3, d3, accB);
    }
    float acc = fmaf(wA, accA, wB * accB);

    // wave (64-lane) reduction; lane 0 stores per-wave partial directly.
    // No LDS, no __syncthreads in the hot kernel.
    #pragma unroll
    for (int off = 32; off > 0; off >>= 1)
        acc += __shfl_down(acc, off, 64);

    if ((threadIdx.x & 63) == 0)
        partials[blockIdx.x * 4 + (threadIdx.x >> 6)] = acc;
}

// Final reduce: 256 threads, 2048 float4 reads in fixed order (deterministic).
__global__ void __launch_bounds__(256) final_reduce_kernel(
        const float4* __restrict__ partials4,
        float* __restrict__ out, float scale) {
    float acc = 0.0f;
    #pragma unroll
    for (int k = 0; k < NWAVES / 4 / 256; ++k) {
        float4 p = partials4[threadIdx.x + k * 256];
        acc += (p.x + p.y) + (p.z + p.w);
    }
    #pragma unroll
    for (int off = 32; off > 0; off >>= 1)
        acc += __shfl_down(acc, off, 64);

    __shared__ float s_part[4];
    int wave = threadIdx.x >> 6;
    int lane = threadIdx.x & 63;
    if (lane == 0) s_part[wave] = acc;
    __syncthreads();
    if (threadIdx.x == 0)
        out[0] = (s_part[0] + s_part[1] + s_part[2] + s_part[3]) * scale;
}

extern "C" void kernel_launch(void* const* d_in, const int* in_sizes, int n_in,
                              void* d_out, int out_size, void* d_ws, size_t ws_size,
                              hipStream_t stream) {
    const float* traj1      = (const float*)d_in[0];
    const float* traj2      = (const float*)d_in[1];
    const float* grid_table = (const float*)d_in[2];
    float* out = (float*)d_out;

    float* partials = (float*)d_ws;    // NWAVES floats = 32 KB

    main_reduce_kernel<<<NBLOCKS, 256, 0, stream>>>(
        (const float4*)traj1, (const float4*)traj2, traj2, grid_table, partials);

    const float scale = 1.0f / (float)(B_LEN * T_LEN * D_LEN);
    final_reduce_kernel<<<1, 256, 0, stream>>>(
        (const float4*)partials, out, scale);
}

// Round 7
// 27.502 us; speedup vs baseline: 1.0638x; 1.0638x over previous
//
#include <hip/hip_runtime.h>

#define GRID_N 100
#define T_LEN 2048
#define B_LEN 4096
#define D_LEN 2
#define NBLOCKS 2048
#define NTHREADS (NBLOCKS * 256)      // 524288
#define UNROLL 8
// n4 = B*T*D/4 = 4,194,304 = NTHREADS * UNROLL exactly (no tail)

__device__ __forceinline__ float w2_at(const float* __restrict__ traj2,
                                       const float* __restrict__ gt, int t) {
    float lat = traj2[2 * t + 0];
    float lon = traj2[2 * t + 1];
    int lat_g = (int)floorf((lat + 1.0f) * 50.0f);
    lat_g = min(max(lat_g, 0), GRID_N - 1);
    int lon_g = (int)floorf((lon + 1.0f) * 50.0f);
    lon_g = min(max(lon_g, 0), GRID_N - 1);
    return gt[lat_g * GRID_N + lon_g] * 0.0001f + 1.0f;
}

__global__ void __launch_bounds__(256) main_reduce_kernel(
        const float4* __restrict__ t1,
        const float4* __restrict__ t2,
        const float* __restrict__ traj2s,
        const float* __restrict__ grid_table,
        float* __restrict__ partials) {
    const int tid = blockIdx.x * 256 + threadIdx.x;

    // Load phase: 16 independent float4 loads in flight
    float4 a[UNROLL], b[UNROLL];
    #pragma unroll
    for (int u = 0; u < UNROLL; ++u) {
        int j = tid + u * NTHREADS;
        a[u] = t1[j];
        b[u] = t2[j];
    }

    // This thread's two time indices (constant across all unrolls since
    // NTHREADS % 1024 == 0): t0 = 2*(tid & 1023), covering (t0, t0+1).
    const int t0 = 2 * (tid & (T_LEN * D_LEN / 4 - 1));
    float wA = w2_at(traj2s, grid_table, t0);
    float wB = w2_at(traj2s, grid_table, t0 + 1);

    float accA = 0.0f, accB = 0.0f;
    #pragma unroll
    for (int u = 0; u < UNROLL; ++u) {
        float d0 = a[u].x - b[u].x;
        float d1 = a[u].y - b[u].y;
        float d2 = a[u].z - b[u].z;
        float d3 = a[u].w - b[u].w;
        accA = fmaf(d0, d0, accA);
        accA = fmaf(d1, d1, accA);
        accB = fmaf(d2, d2, accB);
        accB = fmaf(d3, d3, accB);
    }
    float acc = fmaf(wA, accA, wB * accB);

    // wave (64-lane) reduction
    #pragma unroll
    for (int off = 32; off > 0; off >>= 1)
        acc += __shfl_down(acc, off, 64);

    __shared__ float s_part[4];
    int wave = threadIdx.x >> 6;
    int lane = threadIdx.x & 63;
    if (lane == 0) s_part[wave] = acc;
    __syncthreads();
    if (threadIdx.x == 0)
        partials[blockIdx.x] = s_part[0] + s_part[1] + s_part[2] + s_part[3];
}

// Single-wave final reduce: no LDS, no barrier, 32 unrolled reads + 6 shuffles.
__global__ void __launch_bounds__(64) final_reduce_kernel(
        const float* __restrict__ partials,
        float* __restrict__ out, float scale) {
    float acc = 0.0f;
    #pragma unroll
    for (int k = 0; k < NBLOCKS / 64; ++k)
        acc += partials[threadIdx.x + k * 64];
    #pragma unroll
    for (int off = 32; off > 0; off >>= 1)
        acc += __shfl_down(acc, off, 64);
    if (threadIdx.x == 0)
        out[0] = acc * scale;
}

extern "C" void kernel_launch(void* const* d_in, const int* in_sizes, int n_in,
                              void* d_out, int out_size, void* d_ws, size_t ws_size,
                              hipStream_t stream) {
    const float* traj1      = (const float*)d_in[0];
    const float* traj2      = (const float*)d_in[1];
    const float* grid_table = (const float*)d_in[2];
    float* out = (float*)d_out;

    float* partials = (float*)d_ws;

    main_reduce_kernel<<<NBLOCKS, 256, 0, stream>>>(
        (const float4*)traj1, (const float4*)traj2, traj2, grid_table, partials);

    const float scale = 1.0f / (float)(B_LEN * T_LEN * D_LEN);
    final_reduce_kernel<<<1, 64, 0, stream>>>(partials, out, scale);
}